// Round 1
// baseline (939.141 us; speedup 1.0000x reference)
//
#include <hip/hip_runtime.h>
#include <hip/hip_bf16.h>
#include <math.h>

// ---------------- problem constants ----------------
#define N_     8192
#define WD_    64
#define R_     4
#define OUT_   256
#define IN_    256
#define IFACE_ 471          // R*Wd + 3*Wd + 5*R + 3
#define C_     727          // OUT + IFACE
#define ZC_    2908         // 4*C

// interface offsets
#define OFF_KREAD  0
#define OFF_BREAD  256
#define OFF_KWRITE 260
#define OFF_BWRITE 324
#define OFF_ERASE  325
#define OFF_WRITEV 389
#define OFF_FREEG  453
#define OFF_AGATE  457
#define OFF_WGATE  458
#define OFF_RMODE  459

// ---------------- workspace layout (float offsets) ----------------
#define Z_ACC   0            // 5*2908 = 14540 (atomic acc, zeroed)
#define OVIF    14540        // 727 (atomic acc, zeroed): [0,256)=out_v, [256,727)=iface
#define RV_ACC  15267        // 256 (atomic acc, zeroed)
#define KRH     15523        // 256  k_read_hat
#define BRD     15779        // 4
#define KWH     15783        // 64   k_write_hat
#define BWR     15847        // 1
#define ERS     15848        // 64
#define WRV     15912        // 64
#define FG      15976        // 4
#define AG      15980
#define WG      15981
#define RM      15982        // 12  rm[m*4+r]
#define MXW     15994
#define DENW    15995
#define MXR     15996        // 4
#define DENR    16000        // 4
#define U_      16384        // 8192
#define LOGU    24576        // 8192
#define SCW     32768        // 8192
#define W_      40960        // 8192  (new write weighting)
#define SCR     49152        // 8192*4
#define WRN     81920        // 8192*4 (new read weighting)
#define SPART   114688       // 16*8192
#define MNEW    245760       // 8192*64
#define FWDP    770048       // 32*8192*4
#define BWDP    1818624      // 32*8192*4
// end = 2867200 floats = ~11.5 MB

__device__ __forceinline__ float sigf(float x){ return 1.0f/(1.0f+expf(-x)); }
__device__ __forceinline__ float softplusf_(float x){ return fmaxf(x,0.0f)+log1pf(expf(-fabsf(x))); }
__device__ __forceinline__ float waveSum(float v){
  #pragma unroll
  for (int m=32;m;m>>=1) v += __shfl_xor(v,m);
  return v;
}
__device__ __forceinline__ float waveMax(float v){
  #pragma unroll
  for (int m=32;m;m>>=1) v = fmaxf(v,__shfl_xor(v,m));
  return v;
}

// Recompute LSTM pointwise chain up to step s (exclusive), writing h_s into v727 (LDS).
// blockDim.x must be 256. z_acc holds matvec sums (no bias).
__device__ void lstm_chain(int s, const float* __restrict__ z_acc, const float* __restrict__ lb,
                           const float* __restrict__ h_in, const float* __restrict__ c_in,
                           float* v727){
  int t = threadIdx.x;
  float creg[3];
  #pragma unroll
  for (int k=0;k<3;++k){ int idx=t+256*k; if (idx<C_){ v727[idx]=h_in[idx]; creg[k]=c_in[idx]; } }
  for (int sp=0; sp<s; ++sp){
    #pragma unroll
    for (int k=0;k<3;++k){
      int idx=t+256*k;
      if (idx<C_){
        float zi = z_acc[sp*ZC_ + idx]        + lb[idx];
        float zf = z_acc[sp*ZC_ + C_  + idx]  + lb[C_+idx];
        float zg = z_acc[sp*ZC_ + 2*C_+ idx]  + lb[2*C_+idx];
        float zo = z_acc[sp*ZC_ + 3*C_+ idx]  + lb[3*C_+idx];
        float cn = sigf(zf)*creg[k] + sigf(zi)*tanhf(zg);
        creg[k]=cn;
        v727[idx] = sigf(zo)*tanhf(cn);
      }
    }
  }
}

// One LSTM step: recompute chain for h_s, then partial matvec into z_acc[s].
// grid (12 colblocks, 8 kchunks), block 256.
__global__ __launch_bounds__(256) void k_lstm(const float* __restrict__ x, const float* __restrict__ dk,
    const float* __restrict__ db, const float* __restrict__ lk, const float* __restrict__ lr,
    const float* __restrict__ lb, const float* __restrict__ h_in, const float* __restrict__ c_in,
    const float* __restrict__ read_v, float* __restrict__ ws, int s){
  __shared__ float v[64 + C_];
  int t = threadIdx.x;
  float* z_acc = ws + Z_ACC;
  lstm_chain(s, z_acc, lb, h_in, c_in, v+64);
  if (s == 0){
    if (t < 64){
      float acc = db[t];
      for (int k=0;k<IN_;++k) acc += x[k]*dk[k*64+t];
      v[t]=acc;
    }
  } else {
    if (t < 64) v[t] = read_v[(s-1)*64 + t];
  }
  __syncthreads();
  int col = blockIdx.x*256 + t;
  int k0 = blockIdx.y*99, k1 = min(791, k0+99);
  if (col < ZC_){
    float acc = 0.f;
    for (int k=k0;k<k1;++k){
      float wv = (k<64) ? lk[k*ZC_+col] : lr[(size_t)(k-64)*ZC_+col];
      acc += v[k]*wv;
    }
    atomicAdd(&z_acc[s*ZC_+col], acc);
  }
}

// Final h -> [out_v | iface]. grid (3, 8), block 256.
__global__ __launch_bounds__(256) void k_ovif(const float* __restrict__ lb, const float* __restrict__ h_in,
    const float* __restrict__ c_in, const float* __restrict__ Wo, const float* __restrict__ Wi,
    float* __restrict__ ws){
  __shared__ float v[C_];
  lstm_chain(5, ws+Z_ACC, lb, h_in, c_in, v);
  __syncthreads();
  int t=threadIdx.x;
  int col = blockIdx.x*256 + t;
  int k0 = blockIdx.y*91, k1 = min(C_, k0+91);
  if (col < C_){
    float acc=0.f;
    for (int k=k0;k<k1;++k){
      float wv = (col<OUT_) ? Wo[k*OUT_+col] : Wi[k*IFACE_ + (col-OUT_)];
      acc += v[k]*wv;
    }
    atomicAdd(&ws[OVIF+col], acc);
  }
}

// Parse interface. 1 block, 384 threads (6 waves).
__global__ __launch_bounds__(384) void k_parse(float* __restrict__ ws){
  const float* iface = ws + OVIF + OUT_;
  int t=threadIdx.x, lane=t&63, wv=t>>6;
  if (wv < 4){                       // k_read rows -> normalized
    float val = iface[OFF_KREAD + wv*64 + lane];
    float ss = waveSum(val*val);
    ws[KRH + wv*64 + lane] = val / sqrtf(fmaxf(ss,1e-12f));
  } else if (wv == 4){               // k_write -> normalized
    float val = iface[OFF_KWRITE + lane];
    float ss = waveSum(val*val);
    ws[KWH + lane] = val / sqrtf(fmaxf(ss,1e-12f));
  } else {                           // wave 5: pointwise params
    ws[ERS + lane] = sigf(iface[OFF_ERASE + lane]);
    ws[WRV + lane] = iface[OFF_WRITEV + lane];
    if (lane==0) ws[BWR] = 1.f + softplusf_(iface[OFF_BWRITE]);
    if (lane==1) ws[AG]  = sigf(iface[OFF_AGATE]);
    if (lane==2) ws[WG]  = sigf(iface[OFF_WGATE]);
    if (lane>=4 && lane<8)   ws[BRD + lane-4] = 1.f + softplusf_(iface[OFF_BREAD + lane-4]);
    if (lane>=8 && lane<12)  ws[FG  + lane-8] = sigf(iface[OFF_FREEG + lane-8]);
    if (lane>=12 && lane<16){
      int r = lane-12;
      float m0=iface[OFF_RMODE+r], m1=iface[OFF_RMODE+4+r], m2=iface[OFF_RMODE+8+r];
      float mx=fmaxf(m0,fmaxf(m1,m2));
      float e0=expf(m0-mx), e1=expf(m1-mx), e2=expf(m2-mx);
      float si=1.f/(e0+e1+e2);
      ws[RM+0*4+r]=e0*si; ws[RM+1*4+r]=e1*si; ws[RM+2*4+r]=e2*si;
    }
  }
}

// usage update + write-lookup scores. wave-per-row, grid 2048 x 256.
__global__ __launch_bounds__(256) void k_usage(const float* __restrict__ M, const float* __restrict__ usage,
    const float* __restrict__ Wread, const float* __restrict__ Wwrite, float* __restrict__ ws){
  int t=threadIdx.x, lane=t&63;
  int i = blockIdx.x*4 + (t>>6);
  float ret = (lane<4) ? (1.f - ws[FG+lane]*Wread[i*4+lane]) : 1.f;
  ret *= __shfl_xor(ret,1);
  ret *= __shfl_xor(ret,2);
  float m = M[(size_t)i*64 + lane];
  float ss = waveSum(m*m);
  float dt = waveSum(m * ws[KWH+lane]);
  if (lane==0){
    float us=usage[i], ww=Wwrite[i];
    float u = (us + ww - us*ww)*ret;
    ws[U_+i]=u;
    ws[LOGU+i]=logf(u);
    ws[SCW+i] = ws[BWR]*dt/sqrtf(fmaxf(ss,1e-12f));
  }
}

// softmax stats over write scores. 1 block, 1024 threads.
__global__ __launch_bounds__(1024) void k_softred_w(float* __restrict__ ws){
  __shared__ float red[16];
  __shared__ float sh;
  int t=threadIdx.x;
  float mx=-INFINITY;
  for (int i=t;i<N_;i+=1024) mx=fmaxf(mx,ws[SCW+i]);
  mx=waveMax(mx);
  if ((t&63)==0) red[t>>6]=mx;
  __syncthreads();
  if (t==0){ float v=red[0]; for(int q=1;q<16;++q) v=fmaxf(v,red[q]); sh=v; }
  __syncthreads();
  mx=sh;
  float s=0;
  for (int i=t;i<N_;i+=1024) s+=expf(ws[SCW+i]-mx);
  s=waveSum(s);
  __syncthreads();
  if ((t&63)==0) red[t>>6]=s;
  __syncthreads();
  if (t==0){ float tot=0; for(int q=0;q<16;++q) tot+=red[q]; ws[MXW]=mx; ws[DENW]=tot; }
}

// softmax stats over read scores (4 cols). 1 block, 1024 threads.
__global__ __launch_bounds__(1024) void k_softred_r(float* __restrict__ ws){
  __shared__ float red[16];
  __shared__ float sh;
  int t=threadIdx.x;
  for (int r=0;r<4;++r){
    float mx=-INFINITY;
    for (int i=t;i<N_;i+=1024) mx=fmaxf(mx,ws[SCR+i*4+r]);
    mx=waveMax(mx);
    if ((t&63)==0) red[t>>6]=mx;
    __syncthreads();
    if (t==0){ float v=red[0]; for(int q=1;q<16;++q) v=fmaxf(v,red[q]); sh=v; }
    __syncthreads();
    mx=sh;
    float s=0;
    for (int i=t;i<N_;i+=1024) s+=expf(ws[SCR+i*4+r]-mx);
    s=waveSum(s);
    __syncthreads();
    if ((t&63)==0) red[t>>6]=s;
    __syncthreads();
    if (t==0){ ws[MXR+r]=mx; float tot=0; for(int q=0;q<16;++q) tot+=red[q]; ws[DENR+r]=tot; }
    __syncthreads();
  }
}

// allocation: masked log-sum partials. grid (32 iblocks, 16 kchunks), block 256.
__global__ __launch_bounds__(256) void k_alloc(float* __restrict__ ws){
  __shared__ float us[512], ls[512];
  int t=threadIdx.x;
  int kbase = blockIdx.y*512;
  for (int kk=t; kk<512; kk+=256){ us[kk]=ws[U_+kbase+kk]; ls[kk]=ws[LOGU+kbase+kk]; }
  __syncthreads();
  int i = blockIdx.x*256 + t;
  float ui = ws[U_+i];
  float S = 0.f;
  #pragma unroll 4
  for (int kk=0; kk<512; ++kk){
    float um = us[kk];
    bool sel = (um < ui) || ((um == ui) && ((kbase+kk) < i));
    S += sel ? ls[kk] : 0.f;
  }
  ws[SPART + blockIdx.y*N_ + i] = S;
}

// combine into final write weighting w. grid 32 x 256.
__global__ __launch_bounds__(256) void k_wcomb(float* __restrict__ ws){
  int i = blockIdx.x*256 + threadIdx.x;
  float S=0;
  #pragma unroll
  for (int kb=0;kb<16;++kb) S += ws[SPART+kb*N_+i];
  float alloc = (1.f - ws[U_+i]) * expf(S);
  float lk = expf(ws[SCW+i]-ws[MXW]) / ws[DENW];
  float ag = ws[AG], wg = ws[WG];
  ws[W_+i] = wg*(ag*alloc + (1.f-ag)*lk);
}

// M update + read-lookup scores. wave-per-row, grid 2048 x 256.
__global__ __launch_bounds__(256) void k_mupd(const float* __restrict__ M, float* __restrict__ ws){
  int t=threadIdx.x, lane=t&63;
  int i = blockIdx.x*4 + (t>>6);
  float wi = ws[W_+i];
  float m = M[(size_t)i*64+lane];
  float mn = m*(1.f - wi*ws[ERS+lane]) + wi*ws[WRV+lane];
  ws[MNEW + (size_t)i*64 + lane] = mn;
  float ss = waveSum(mn*mn);
  float d0 = waveSum(mn*ws[KRH+  0+lane]);
  float d1 = waveSum(mn*ws[KRH+ 64+lane]);
  float d2 = waveSum(mn*ws[KRH+128+lane]);
  float d3 = waveSum(mn*ws[KRH+192+lane]);
  if (lane==0){
    float inv = 1.f/sqrtf(fmaxf(ss,1e-12f));
    ws[SCR+i*4+0]=ws[BRD+0]*d0*inv;
    ws[SCR+i*4+1]=ws[BRD+1]*d1*inv;
    ws[SCR+i*4+2]=ws[BRD+2]*d2*inv;
    ws[SCR+i*4+3]=ws[BRD+3]*d3*inv;
  }
}

// THE heavy pass: stream L once, fuse temporal-link update into fwd/bwd reductions.
// grid (32 jb, 32 ib), block 256. Writes partials to ws.
__global__ __launch_bounds__(256) void k_lpass(const float* __restrict__ L, const float* __restrict__ Wprec,
    const float* __restrict__ Wread, float* __restrict__ ws){
  __shared__ float  wi_s[256];
  __shared__ float4 wr_s[256];
  __shared__ float4 fp[4][256];
  int t=threadIdx.x, lane=t&63, wv=t>>6;
  int j0 = blockIdx.x*256, i0 = blockIdx.y*256;
  int j = j0 + t;
  float wj = ws[W_+j];
  float pj = Wprec[j];
  float4 wrj = ((const float4*)Wread)[j];
  wi_s[t] = ws[W_+i0+t];
  wr_s[t] = ((const float4*)Wread)[i0+t];
  __syncthreads();
  float b0=0,b1=0,b2=0,b3=0;
  for (int ir=0; ir<256; ++ir){
    int i = i0 + ir;
    float Lij = L[(size_t)i*N_ + j];
    float wi = wi_s[ir];
    float Ln = (1.f - wi - wj)*Lij + wi*pj;
    if (i == j) Ln = 0.f;
    float4 wri = wr_s[ir];
    b0 += Ln*wri.x; b1 += Ln*wri.y; b2 += Ln*wri.z; b3 += Ln*wri.w;
    float f0 = waveSum(Ln*wrj.x);
    float f1 = waveSum(Ln*wrj.y);
    float f2 = waveSum(Ln*wrj.z);
    float f3 = waveSum(Ln*wrj.w);
    if (lane==0) fp[wv][ir] = make_float4(f0,f1,f2,f3);
  }
  __syncthreads();
  {
    int ir = t;
    float4 a=fp[0][ir], b=fp[1][ir], c=fp[2][ir], d=fp[3][ir];
    float4 s = make_float4(a.x+b.x+c.x+d.x, a.y+b.y+c.y+d.y, a.z+b.z+c.z+d.z, a.w+b.w+c.w+d.w);
    ((float4*)(ws+FWDP))[(size_t)blockIdx.x*N_ + i0 + ir] = s;
  }
  ((float4*)(ws+BWDP))[(size_t)blockIdx.y*N_ + j] = make_float4(b0,b1,b2,b3);
}

// reduce partials -> W_read_new. grid 32 x 256.
__global__ __launch_bounds__(256) void k_red(float* __restrict__ ws){
  int i = blockIdx.x*256 + threadIdx.x;
  float4 f = make_float4(0,0,0,0), b = make_float4(0,0,0,0);
  #pragma unroll 4
  for (int q=0;q<32;++q){
    float4 a = ((const float4*)(ws+FWDP))[(size_t)q*N_+i];
    f.x+=a.x; f.y+=a.y; f.z+=a.z; f.w+=a.w;
    float4 c = ((const float4*)(ws+BWDP))[(size_t)q*N_+i];
    b.x+=c.x; b.y+=c.y; b.z+=c.z; b.w+=c.w;
  }
  float wrn[4];
  float fa[4]={f.x,f.y,f.z,f.w}, ba[4]={b.x,b.y,b.z,b.w};
  #pragma unroll
  for (int r=0;r<4;++r){
    float lk = expf(ws[SCR+i*4+r]-ws[MXR+r]) / ws[DENR+r];
    wrn[r] = ws[RM+0*4+r]*ba[r] + ws[RM+1*4+r]*lk + ws[RM+2*4+r]*fa[r];
  }
  ((float4*)(ws+WRN))[i] = make_float4(wrn[0],wrn[1],wrn[2],wrn[3]);
}

// read_v_new[r][d] = sum_i Wrn[i][r]*Mnew[i][d]. grid 32 x 256, atomics into RV_ACC.
__global__ __launch_bounds__(256) void k_rv(float* __restrict__ ws){
  __shared__ float4 wl[256];
  int t=threadIdx.x;
  int i0 = blockIdx.x*256;
  wl[t] = ((const float4*)(ws+WRN))[i0+t];
  __syncthreads();
  int r = t>>6, d = t&63;
  float acc=0;
  for (int ii=0;ii<256;++ii){
    float m = ws[MNEW + (size_t)(i0+ii)*64 + d];
    float wv = ((const float*)&wl[ii])[r];
    acc += m*wv;
  }
  atomicAdd(&ws[RV_ACC + r*64 + d], acc);
}

// y = out_v + rv_flat @ W_read_out. 1 block, 256 threads.
__global__ __launch_bounds__(256) void k_y(const float* __restrict__ Wro, const float* __restrict__ ws,
                                           float* __restrict__ out){
  int o = threadIdx.x;
  float acc = ws[OVIF + o];
  for (int k=0;k<256;++k) acc += ws[RV_ACC+k]*Wro[k*256+o];
  out[o] = acc;
}

extern "C" void kernel_launch(void* const* d_in, const int* in_sizes, int n_in,
                              void* d_out, int out_size, void* d_ws, size_t ws_size,
                              hipStream_t stream) {
  const float* x     = (const float*)d_in[0];
  const float* dk    = (const float*)d_in[1];
  const float* db    = (const float*)d_in[2];
  const float* lk    = (const float*)d_in[3];
  const float* lr    = (const float*)d_in[4];
  const float* lb    = (const float*)d_in[5];
  const float* Wo    = (const float*)d_in[6];
  const float* Wi    = (const float*)d_in[7];
  const float* Wro   = (const float*)d_in[8];
  const float* h     = (const float*)d_in[9];
  const float* c     = (const float*)d_in[10];
  const float* M     = (const float*)d_in[11];
  const float* usage = (const float*)d_in[12];
  const float* L     = (const float*)d_in[13];
  const float* Wprec = (const float*)d_in[14];
  const float* Wread = (const float*)d_in[15];
  const float* Wwrite= (const float*)d_in[16];
  const float* readv = (const float*)d_in[17];
  float* ws = (float*)d_ws;
  float* out = (float*)d_out;

  // zero the atomic-accumulation + params region (first 16384 floats)
  hipMemsetAsync(d_ws, 0, 16384*sizeof(float), stream);

  for (int s=0;s<5;++s)
    k_lstm<<<dim3(12,8),256,0,stream>>>(x,dk,db,lk,lr,lb,h,c,readv,ws,s);
  k_ovif<<<dim3(3,8),256,0,stream>>>(lb,h,c,Wo,Wi,ws);
  k_parse<<<1,384,0,stream>>>(ws);
  k_usage<<<2048,256,0,stream>>>(M,usage,Wread,Wwrite,ws);
  k_softred_w<<<1,1024,0,stream>>>(ws);
  k_alloc<<<dim3(32,16),256,0,stream>>>(ws);
  k_wcomb<<<32,256,0,stream>>>(ws);
  k_mupd<<<2048,256,0,stream>>>(M,ws);
  k_softred_r<<<1,1024,0,stream>>>(ws);
  k_lpass<<<dim3(32,32),256,0,stream>>>(L,Wprec,Wread,ws);
  k_red<<<32,256,0,stream>>>(ws);
  k_rv<<<32,256,0,stream>>>(ws);
  k_y<<<1,256,0,stream>>>(Wro,ws,out);
}

// Round 3
// 655.581 us; speedup vs baseline: 1.4325x; 1.4325x over previous
//
#include <hip/hip_runtime.h>
#include <hip/hip_bf16.h>
#include <math.h>

// ---------------- problem constants ----------------
#define N_     8192
#define WD_    64
#define R_     4
#define OUT_   256
#define IN_    256
#define IFACE_ 471          // R*Wd + 3*Wd + 5*R + 3
#define C_     727          // OUT + IFACE
#define ZC_    2908         // 4*C

// interface offsets
#define OFF_KREAD  0
#define OFF_BREAD  256
#define OFF_KWRITE 260
#define OFF_BWRITE 324
#define OFF_ERASE  325
#define OFF_WRITEV 389
#define OFF_FREEG  453
#define OFF_AGATE  457
#define OFF_WGATE  458
#define OFF_RMODE  459

// ---------------- workspace layout (float offsets) ----------------
// zeroed region [0, 81920)
#define Z_ACC   0            // 5*2908 = 14540 (atomic acc)
#define OVIF    14540        // 727 (atomic acc): [0,256)=out_v, [256,727)=iface
#define RV_ACC  15267        // 256 (atomic acc)
#define FWD     16384        // SoA: plane r at FWD + r*8192, 4*8192 (atomic acc)
#define BWD     49152        // SoA: plane r at BWD + r*8192, 4*8192 (atomic acc)
// params (overwritten each launch)
#define KRH     81920        // 256
#define BRD     82176        // 4
#define KWH     82180        // 64
#define BWR     82244        // 1
#define ERS     82245        // 64
#define WRV     82309        // 64
#define FG      82373        // 4
#define AG      82377
#define WG      82378
#define RM      82379        // 12  rm[m*4+r]
#define MXW     82391
#define DENW    82392
#define MXR     82393        // 4
#define DENR    82397        // 4
#define U_      90112        // 8192
#define LOGU    98304        // 8192
#define SCW     106496       // 8192
#define W_      114688       // 8192  (new write weighting)
#define SCR     122880       // 8192*4
#define SPART   155648       // 16*8192
#define MNEW    286720       // 8192*64 -> ends 811008 floats (~3.2 MB)

__device__ __forceinline__ float sigf(float x){ return 1.0f/(1.0f+expf(-x)); }
__device__ __forceinline__ float softplusf_(float x){ return fmaxf(x,0.0f)+log1pf(expf(-fabsf(x))); }
__device__ __forceinline__ float waveSum(float v){
  #pragma unroll
  for (int m=32;m;m>>=1) v += __shfl_xor(v,m);
  return v;
}
__device__ __forceinline__ float waveMax(float v){
  #pragma unroll
  for (int m=32;m;m>>=1) v = fmaxf(v,__shfl_xor(v,m));
  return v;
}

// Recompute LSTM pointwise chain up to step s (exclusive), writing h_s into v727 (LDS).
__device__ void lstm_chain(int s, const float* __restrict__ z_acc, const float* __restrict__ lb,
                           const float* __restrict__ h_in, const float* __restrict__ c_in,
                           float* v727){
  int t = threadIdx.x;
  float creg[3];
  #pragma unroll
  for (int k=0;k<3;++k){ int idx=t+256*k; if (idx<C_){ v727[idx]=h_in[idx]; creg[k]=c_in[idx]; } }
  for (int sp=0; sp<s; ++sp){
    #pragma unroll
    for (int k=0;k<3;++k){
      int idx=t+256*k;
      if (idx<C_){
        float zi = z_acc[sp*ZC_ + idx]        + lb[idx];
        float zf = z_acc[sp*ZC_ + C_  + idx]  + lb[C_+idx];
        float zg = z_acc[sp*ZC_ + 2*C_+ idx]  + lb[2*C_+idx];
        float zo = z_acc[sp*ZC_ + 3*C_+ idx]  + lb[3*C_+idx];
        float cn = sigf(zf)*creg[k] + sigf(zi)*tanhf(zg);
        creg[k]=cn;
        v727[idx] = sigf(zo)*tanhf(cn);
      }
    }
  }
}

// One LSTM step. grid (12 colblocks, 16 kchunks), block 256.
__global__ __launch_bounds__(256) void k_lstm(const float* __restrict__ x, const float* __restrict__ dk,
    const float* __restrict__ db, const float* __restrict__ lk, const float* __restrict__ lr,
    const float* __restrict__ lb, const float* __restrict__ h_in, const float* __restrict__ c_in,
    const float* __restrict__ read_v, float* __restrict__ ws, int s){
  __shared__ float v[64 + C_];
  int t = threadIdx.x;
  float* z_acc = ws + Z_ACC;
  lstm_chain(s, z_acc, lb, h_in, c_in, v+64);
  if (s == 0){
    if (t < 64){
      float acc = db[t];
      for (int k=0;k<IN_;++k) acc += x[k]*dk[k*64+t];
      v[t]=acc;
    }
  } else {
    if (t < 64) v[t] = read_v[(s-1)*64 + t];
  }
  __syncthreads();
  int col = blockIdx.x*256 + t;
  int k0 = blockIdx.y*50, k1 = min(791, k0+50);
  if (col < ZC_){
    float acc = 0.f;
    for (int k=k0;k<k1;++k){
      float wv = (k<64) ? lk[k*ZC_+col] : lr[(size_t)(k-64)*ZC_+col];
      acc += v[k]*wv;
    }
    atomicAdd(&z_acc[s*ZC_+col], acc);
  }
}

// Final h -> [out_v | iface]. grid (3, 16), block 256.
__global__ __launch_bounds__(256) void k_ovif(const float* __restrict__ lb, const float* __restrict__ h_in,
    const float* __restrict__ c_in, const float* __restrict__ Wo, const float* __restrict__ Wi,
    float* __restrict__ ws){
  __shared__ float v[C_];
  lstm_chain(5, ws+Z_ACC, lb, h_in, c_in, v);
  __syncthreads();
  int t=threadIdx.x;
  int col = blockIdx.x*256 + t;
  int k0 = blockIdx.y*46, k1 = min(C_, k0+46);
  if (col < C_){
    float acc=0.f;
    for (int k=k0;k<k1;++k){
      float wv = (col<OUT_) ? Wo[k*OUT_+col] : Wi[k*IFACE_ + (col-OUT_)];
      acc += v[k]*wv;
    }
    atomicAdd(&ws[OVIF+col], acc);
  }
}

// Parse interface. 1 block, 384 threads.
__global__ __launch_bounds__(384) void k_parse(float* __restrict__ ws){
  const float* iface = ws + OVIF + OUT_;
  int t=threadIdx.x, lane=t&63, wv=t>>6;
  if (wv < 4){
    float val = iface[OFF_KREAD + wv*64 + lane];
    float ss = waveSum(val*val);
    ws[KRH + wv*64 + lane] = val / sqrtf(fmaxf(ss,1e-12f));
  } else if (wv == 4){
    float val = iface[OFF_KWRITE + lane];
    float ss = waveSum(val*val);
    ws[KWH + lane] = val / sqrtf(fmaxf(ss,1e-12f));
  } else {
    ws[ERS + lane] = sigf(iface[OFF_ERASE + lane]);
    ws[WRV + lane] = iface[OFF_WRITEV + lane];
    if (lane==0) ws[BWR] = 1.f + softplusf_(iface[OFF_BWRITE]);
    if (lane==1) ws[AG]  = sigf(iface[OFF_AGATE]);
    if (lane==2) ws[WG]  = sigf(iface[OFF_WGATE]);
    if (lane>=4 && lane<8)   ws[BRD + lane-4] = 1.f + softplusf_(iface[OFF_BREAD + lane-4]);
    if (lane>=8 && lane<12)  ws[FG  + lane-8] = sigf(iface[OFF_FREEG + lane-8]);
    if (lane>=12 && lane<16){
      int r = lane-12;
      float m0=iface[OFF_RMODE+r], m1=iface[OFF_RMODE+4+r], m2=iface[OFF_RMODE+8+r];
      float mx=fmaxf(m0,fmaxf(m1,m2));
      float e0=expf(m0-mx), e1=expf(m1-mx), e2=expf(m2-mx);
      float si=1.f/(e0+e1+e2);
      ws[RM+0*4+r]=e0*si; ws[RM+1*4+r]=e1*si; ws[RM+2*4+r]=e2*si;
    }
  }
}

// usage update + write-lookup scores. wave-per-row, grid 2048 x 256.
__global__ __launch_bounds__(256) void k_usage(const float* __restrict__ M, const float* __restrict__ usage,
    const float* __restrict__ Wread, const float* __restrict__ Wwrite, float* __restrict__ ws){
  int t=threadIdx.x, lane=t&63;
  int i = blockIdx.x*4 + (t>>6);
  float ret = (lane<4) ? (1.f - ws[FG+lane]*Wread[i*4+lane]) : 1.f;
  ret *= __shfl_xor(ret,1);
  ret *= __shfl_xor(ret,2);
  float m = M[(size_t)i*64 + lane];
  float ss = waveSum(m*m);
  float dt = waveSum(m * ws[KWH+lane]);
  if (lane==0){
    float us=usage[i], ww=Wwrite[i];
    float u = (us + ww - us*ww)*ret;
    ws[U_+i]=u;
    ws[LOGU+i]=logf(u);
    ws[SCW+i] = ws[BWR]*dt/sqrtf(fmaxf(ss,1e-12f));
  }
}

// softmax stats over write scores. 1 block, 1024 threads.
__global__ __launch_bounds__(1024) void k_softred_w(float* __restrict__ ws){
  __shared__ float red[16];
  __shared__ float sh;
  int t=threadIdx.x;
  float mx=-INFINITY;
  for (int i=t;i<N_;i+=1024) mx=fmaxf(mx,ws[SCW+i]);
  mx=waveMax(mx);
  if ((t&63)==0) red[t>>6]=mx;
  __syncthreads();
  if (t==0){ float v=red[0]; for(int q=1;q<16;++q) v=fmaxf(v,red[q]); sh=v; }
  __syncthreads();
  mx=sh;
  float s=0;
  for (int i=t;i<N_;i+=1024) s+=expf(ws[SCW+i]-mx);
  s=waveSum(s);
  __syncthreads();
  if ((t&63)==0) red[t>>6]=s;
  __syncthreads();
  if (t==0){ float tot=0; for(int q=0;q<16;++q) tot+=red[q]; ws[MXW]=mx; ws[DENW]=tot; }
}

// softmax stats over read scores, parallel over r. 1 block, 1024 threads.
__global__ __launch_bounds__(1024) void k_softred_r(float* __restrict__ ws){
  __shared__ float red[16][4];
  __shared__ float mxs[4];
  int t=threadIdx.x, r=t&3;
  float mx=-INFINITY;
  for (int i=(t>>2); i<N_; i+=256) mx=fmaxf(mx, ws[SCR+i*4+r]);
  #pragma unroll
  for (int m=4;m<64;m<<=1) mx=fmaxf(mx,__shfl_xor(mx,m));
  if ((t&63)<4) red[t>>6][r]=mx;
  __syncthreads();
  if (t<4){ float v=red[0][r]; for(int q=1;q<16;++q) v=fmaxf(v,red[q][r]); mxs[r]=v; ws[MXR+r]=v; }
  __syncthreads();
  mx = mxs[r];
  float s=0;
  for (int i=(t>>2); i<N_; i+=256) s+=expf(ws[SCR+i*4+r]-mx);
  #pragma unroll
  for (int m=4;m<64;m<<=1) s+=__shfl_xor(s,m);
  if ((t&63)<4) red[t>>6][r]=s;
  __syncthreads();
  if (t<4){ float v=0; for(int q=0;q<16;++q) v+=red[q][r]; ws[DENR+r]=v; }
}

// allocation: masked log-sum partials. grid (32 iblocks, 16 kchunks), block 256.
__global__ __launch_bounds__(256) void k_alloc(float* __restrict__ ws){
  __shared__ float us[512], ls[512];
  int t=threadIdx.x;
  int kbase = blockIdx.y*512;
  for (int kk=t; kk<512; kk+=256){ us[kk]=ws[U_+kbase+kk]; ls[kk]=ws[LOGU+kbase+kk]; }
  __syncthreads();
  int i = blockIdx.x*256 + t;
  float ui = ws[U_+i];
  float S = 0.f;
  #pragma unroll 4
  for (int kk=0; kk<512; ++kk){
    float um = us[kk];
    bool sel = (um < ui) || ((um == ui) && ((kbase+kk) < i));
    S += sel ? ls[kk] : 0.f;
  }
  ws[SPART + blockIdx.y*N_ + i] = S;
}

// combine into final write weighting w. grid 32 x 256.
__global__ __launch_bounds__(256) void k_wcomb(float* __restrict__ ws){
  int i = blockIdx.x*256 + threadIdx.x;
  float S=0;
  #pragma unroll
  for (int kb=0;kb<16;++kb) S += ws[SPART+kb*N_+i];
  float alloc = (1.f - ws[U_+i]) * expf(S);
  float lk = expf(ws[SCW+i]-ws[MXW]) / ws[DENW];
  float ag = ws[AG], wg = ws[WG];
  ws[W_+i] = wg*(ag*alloc + (1.f-ag)*lk);
}

// M update + read-lookup scores. wave-per-row, grid 2048 x 256.
__global__ __launch_bounds__(256) void k_mupd(const float* __restrict__ M, float* __restrict__ ws){
  int t=threadIdx.x, lane=t&63;
  int i = blockIdx.x*4 + (t>>6);
  float wi = ws[W_+i];
  float m = M[(size_t)i*64+lane];
  float mn = m*(1.f - wi*ws[ERS+lane]) + wi*ws[WRV+lane];
  ws[MNEW + (size_t)i*64 + lane] = mn;
  float ss = waveSum(mn*mn);
  float d0 = waveSum(mn*ws[KRH+  0+lane]);
  float d1 = waveSum(mn*ws[KRH+ 64+lane]);
  float d2 = waveSum(mn*ws[KRH+128+lane]);
  float d3 = waveSum(mn*ws[KRH+192+lane]);
  if (lane==0){
    float inv = 1.f/sqrtf(fmaxf(ss,1e-12f));
    ws[SCR+i*4+0]=ws[BRD+0]*d0*inv;
    ws[SCR+i*4+1]=ws[BRD+1]*d1*inv;
    ws[SCR+i*4+2]=ws[BRD+2]*d2*inv;
    ws[SCR+i*4+3]=ws[BRD+3]*d3*inv;
  }
}

// Heavy pass, shuffle-free: stage 128x128 L tile in LDS (stride 129 -> conflict-free
// both orientations), register-accumulate bwd (col-owner) and fwd (row-owner),
// coalesced SoA atomics into FWD/BWD. grid (64 jb, 64 ib), block 256.
#define LT   128
#define LSTR 129
__global__ __launch_bounds__(256) void k_lpass(const float* __restrict__ L, const float* __restrict__ Wprec,
    const float* __restrict__ Wread, float* __restrict__ ws){
  __shared__ float tile[LT*LSTR];
  __shared__ float wi_s[LT], wj_s[LT], pj_s[LT];
  __shared__ float4 wri_s[LT], wrj_s[LT];
  int t = threadIdx.x;
  int i0 = blockIdx.y*LT, j0 = blockIdx.x*LT;
  if (t < LT){
    wi_s[t]  = ws[W_+i0+t];
    wri_s[t] = ((const float4*)Wread)[i0+t];
  } else {
    int c = t-LT;
    wj_s[c]  = ws[W_+j0+c];
    pj_s[c]  = Wprec[j0+c];
    wrj_s[c] = ((const float4*)Wread)[j0+c];
  }
  #pragma unroll
  for (int q=0;q<16;++q){
    int m = q*256+t;
    int r = m>>5, s = m&31;
    float4 v = *(const float4*)&L[(size_t)(i0+r)*N_ + j0 + 4*s];
    float* dst = &tile[r*LSTR + 4*s];
    dst[0]=v.x; dst[1]=v.y; dst[2]=v.z; dst[3]=v.w;
  }
  __syncthreads();
  // Phase A: bwd[j] = sum_i Ln(i,j)*wr_i
  {
    int c = t & 127, h = t>>7;
    float wj = wj_s[c], pj = pj_s[c];
    int j = j0 + c;
    float b0=0,b1=0,b2=0,b3=0;
    #pragma unroll 4
    for (int ir=0; ir<64; ++ir){
      int rr = h*64+ir;
      float Lij = tile[rr*LSTR + c];
      float wi = wi_s[rr];
      float Ln = (1.f-wi-wj)*Lij + wi*pj;
      if (i0+rr == j) Ln = 0.f;
      float4 wri = wri_s[rr];
      b0 += Ln*wri.x; b1 += Ln*wri.y; b2 += Ln*wri.z; b3 += Ln*wri.w;
    }
    atomicAdd(&ws[BWD + 0*N_ + j], b0);
    atomicAdd(&ws[BWD + 1*N_ + j], b1);
    atomicAdd(&ws[BWD + 2*N_ + j], b2);
    atomicAdd(&ws[BWD + 3*N_ + j], b3);
  }
  // Phase B: fwd[i] = sum_j Ln(i,j)*wr_j
  {
    int rr = t & 127, q = t>>7;
    float wi = wi_s[rr];
    int i = i0 + rr;
    float f0=0,f1=0,f2=0,f3=0;
    #pragma unroll 4
    for (int cc=0; cc<64; ++cc){
      int c = q*64+cc;
      float Lij = tile[rr*LSTR + c];
      float wj = wj_s[c], pj = pj_s[c];
      float Ln = (1.f-wi-wj)*Lij + wi*pj;
      if (i == j0+c) Ln = 0.f;
      float4 wrj = wrj_s[c];
      f0 += Ln*wrj.x; f1 += Ln*wrj.y; f2 += Ln*wrj.z; f3 += Ln*wrj.w;
    }
    atomicAdd(&ws[FWD + 0*N_ + i], f0);
    atomicAdd(&ws[FWD + 1*N_ + i], f1);
    atomicAdd(&ws[FWD + 2*N_ + i], f2);
    atomicAdd(&ws[FWD + 3*N_ + i], f3);
  }
}

// fused: W_read_new from FWD/BWD/lookup, then read_v partial matvec. grid 32 x 256.
__global__ __launch_bounds__(256) void k_rv(float* __restrict__ ws){
  __shared__ float4 wl[256];
  int t=threadIdx.x;
  int i0 = blockIdx.x*256;
  int i = i0 + t;
  float wrn[4];
  #pragma unroll
  for (int r=0;r<4;++r){
    float f = ws[FWD + r*N_ + i];
    float b = ws[BWD + r*N_ + i];
    float lk = expf(ws[SCR+i*4+r]-ws[MXR+r]) / ws[DENR+r];
    wrn[r] = ws[RM+0*4+r]*b + ws[RM+1*4+r]*lk + ws[RM+2*4+r]*f;
  }
  wl[t] = make_float4(wrn[0],wrn[1],wrn[2],wrn[3]);
  __syncthreads();
  int r = t>>6, d = t&63;
  float acc=0;
  for (int ii=0;ii<256;++ii){
    float m = ws[MNEW + (size_t)(i0+ii)*64 + d];
    float wv = ((const float*)&wl[ii])[r];
    acc += m*wv;
  }
  atomicAdd(&ws[RV_ACC + r*64 + d], acc);
}

// y = out_v + rv_flat @ W_read_out. 1 block, 256 threads.
__global__ __launch_bounds__(256) void k_y(const float* __restrict__ Wro, const float* __restrict__ ws,
                                           float* __restrict__ out){
  int o = threadIdx.x;
  float acc = ws[OVIF + o];
  for (int k=0;k<256;++k) acc += ws[RV_ACC+k]*Wro[k*256+o];
  out[o] = acc;
}

extern "C" void kernel_launch(void* const* d_in, const int* in_sizes, int n_in,
                              void* d_out, int out_size, void* d_ws, size_t ws_size,
                              hipStream_t stream) {
  const float* x     = (const float*)d_in[0];
  const float* dk    = (const float*)d_in[1];
  const float* db    = (const float*)d_in[2];
  const float* lk    = (const float*)d_in[3];
  const float* lr    = (const float*)d_in[4];
  const float* lb    = (const float*)d_in[5];
  const float* Wo    = (const float*)d_in[6];
  const float* Wi    = (const float*)d_in[7];
  const float* Wro   = (const float*)d_in[8];
  const float* h     = (const float*)d_in[9];
  const float* c     = (const float*)d_in[10];
  const float* M     = (const float*)d_in[11];
  const float* usage = (const float*)d_in[12];
  const float* L     = (const float*)d_in[13];
  const float* Wprec = (const float*)d_in[14];
  const float* Wread = (const float*)d_in[15];
  const float* Wwrite= (const float*)d_in[16];
  const float* readv = (const float*)d_in[17];
  float* ws = (float*)d_ws;
  float* out = (float*)d_out;

  // zero atomic-accumulation regions: z_acc, ovif, rv_acc, FWD, BWD
  hipMemsetAsync(d_ws, 0, 81920*sizeof(float), stream);

  for (int s=0;s<5;++s)
    k_lstm<<<dim3(12,16),256,0,stream>>>(x,dk,db,lk,lr,lb,h,c,readv,ws,s);
  k_ovif<<<dim3(3,16),256,0,stream>>>(lb,h,c,Wo,Wi,ws);
  k_parse<<<1,384,0,stream>>>(ws);
  k_usage<<<2048,256,0,stream>>>(M,usage,Wread,Wwrite,ws);
  k_softred_w<<<1,1024,0,stream>>>(ws);
  k_alloc<<<dim3(32,16),256,0,stream>>>(ws);
  k_wcomb<<<32,256,0,stream>>>(ws);
  k_mupd<<<2048,256,0,stream>>>(M,ws);
  k_softred_r<<<1,1024,0,stream>>>(ws);
  k_lpass<<<dim3(64,64),256,0,stream>>>(L,Wprec,Wread,ws);
  k_rv<<<32,256,0,stream>>>(ws);
  k_y<<<1,256,0,stream>>>(Wro,ws,out);
}